// Round 3
// baseline (382.402 us; speedup 1.0000x reference)
//
#include <hip/hip_runtime.h>
#include <math.h>

#define HH 1024
#define SS 1024
#define EE 3

typedef __bf16 bf16x8 __attribute__((ext_vector_type(8)));
typedef float floatx4 __attribute__((ext_vector_type(4)));

__device__ __forceinline__ unsigned short f2bf(float f) {
  union { float f; unsigned u; } v; v.f = f;
  unsigned r = 0x7FFFu + ((v.u >> 16) & 1u);
  return (unsigned short)((v.u + r) >> 16);
}
__device__ __forceinline__ unsigned pack2(float lo, float hi) {
  return ((unsigned)f2bf(hi) << 16) | (unsigned)f2bf(lo);
}

// ---------------- kernel 1: routing (logits -> argmax, gate) ----------------
__global__ __launch_bounds__(256) void k_route(
    const float* __restrict__ x,    // [B,3,S,H] fp32
    const float* __restrict__ wg,   // [3,H,3]   fp32
    int* __restrict__ idx_out,      // [3*T]
    float* __restrict__ gv_out,     // [3*T]
    int T) {
  int wid = (blockIdx.x * 256 + threadIdx.x) >> 6;  // one wave per (branch, token)
  int lane = threadIdx.x & 63;
  if (wid >= 3 * T) return;
  int r = wid / T;
  int t = wid - r * T;
  const float* xrow = x + (size_t)(((t >> 10) * 3 + r) * SS + (t & 1023)) * HH;
  const float* w = wg + (size_t)r * HH * EE;

  double a0 = 0, a1 = 0, a2 = 0;
#pragma unroll
  for (int c = 0; c < 2; ++c) {
    int h0 = c * 512 + lane * 8;  // 8 contiguous h per lane per chunk
    float4 xa = *reinterpret_cast<const float4*>(xrow + h0);
    float4 xb = *reinterpret_cast<const float4*>(xrow + h0 + 4);
    float xs[8] = {xa.x, xa.y, xa.z, xa.w, xb.x, xb.y, xb.z, xb.w};
    union { float4 q[6]; float f[24]; } wv;  // 24 contiguous gate floats
    const float4* wp = reinterpret_cast<const float4*>(w + (size_t)h0 * 3);
#pragma unroll
    for (int j = 0; j < 6; ++j) wv.q[j] = wp[j];
#pragma unroll
    for (int j = 0; j < 8; ++j) {
      double xv = (double)xs[j];
      a0 += xv * (double)wv.f[3 * j + 0];
      a1 += xv * (double)wv.f[3 * j + 1];
      a2 += xv * (double)wv.f[3 * j + 2];
    }
  }
#pragma unroll
  for (int d = 32; d >= 1; d >>= 1) {
    a0 += __shfl_down(a0, d, 64);
    a1 += __shfl_down(a1, d, 64);
    a2 += __shfl_down(a2, d, 64);
  }
  if (lane == 0) {
    int best = 0; double bl = a0;
    if (a1 > bl) { best = 1; bl = a1; }  // strict >: first-max wins (jnp.argmax)
    if (a2 > bl) { best = 2; bl = a2; }
    float g = 1.0f / (expf((float)(a0 - bl)) + expf((float)(a1 - bl)) +
                      expf((float)(a2 - bl)));
    idx_out[wid] = best;
    gv_out[wid] = g;
  }
}

// ---------------- kernel 2: arrival-order scan + expert lists ----------------
__global__ __launch_bounds__(1024) void k_scan(
    const int* __restrict__ idx, const float* __restrict__ gv,
    int* __restrict__ perm,    // [3*3*T] token ids per (branch,expert), arrival order
    float* __restrict__ scale, // [3*T]  gate*keep (0 if dropped)
    int* __restrict__ counts,  // [9]
    int T, int C) {
  int r = blockIdx.x;
  int tid = threadIdx.x;
  int per = T >> 10;  // tokens per thread (T=8192 -> 8)
  int t0 = tid * per;
  const int* idxr = idx + (size_t)r * T;

  int c0 = 0, c1 = 0, c2 = 0;
  for (int k = 0; k < per; ++k) {
    int e = idxr[t0 + k];
    c0 += (e == 0); c1 += (e == 1); c2 += (e == 2);
  }
  int lane = tid & 63, wv = tid >> 6;
  int s0 = c0, s1 = c1, s2 = c2;  // wave inclusive scan
  for (int d = 1; d < 64; d <<= 1) {
    int u0 = __shfl_up(s0, d, 64);
    int u1 = __shfl_up(s1, d, 64);
    int u2 = __shfl_up(s2, d, 64);
    if (lane >= d) { s0 += u0; s1 += u1; s2 += u2; }
  }
  __shared__ int wsum[16][3];
  __shared__ int wbase[16][3];
  if (lane == 63) { wsum[wv][0] = s0; wsum[wv][1] = s1; wsum[wv][2] = s2; }
  __syncthreads();
  if (tid == 0) {
    int b0 = 0, b1 = 0, b2 = 0;
    int nw = blockDim.x >> 6;
    for (int i = 0; i < nw; ++i) {
      wbase[i][0] = b0; wbase[i][1] = b1; wbase[i][2] = b2;
      b0 += wsum[i][0]; b1 += wsum[i][1]; b2 += wsum[i][2];
    }
    counts[r * 3 + 0] = b0; counts[r * 3 + 1] = b1; counts[r * 3 + 2] = b2;
  }
  __syncthreads();
  int off[3];
  off[0] = wbase[wv][0] + s0 - c0;
  off[1] = wbase[wv][1] + s1 - c1;
  off[2] = wbase[wv][2] + s2 - c2;
  for (int k = 0; k < per; ++k) {
    int e = idxr[t0 + k];
    int p = off[e]++;
    perm[(size_t)(r * 3 + e) * T + p] = t0 + k;
    scale[(size_t)r * T + t0 + k] = (p < C) ? gv[(size_t)r * T + t0 + k] : 0.0f;
  }
}

// ---------------- kernel 3: grouped GEMM (gathered A rows) ----------------
// fp32 global -> bf16 LDS tiles, 128x128 tile, BK=32, 4 waves (2x2 of 64x64),
// mfma_f32_16x16x32_bf16, fp32 epilogue (bias + gate scale).
__global__ __launch_bounds__(256) void k_gemm(
    const float* __restrict__ x,    // [B,3,S,H]
    const float* __restrict__ We,   // [3,3,H,H] (out-major: W[o][h])
    const float* __restrict__ be,   // [3,3,H]
    const int* __restrict__ perm, const float* __restrict__ scale,
    const int* __restrict__ counts,
    float* __restrict__ out,        // [B,3,S,H]
    int T) {
  int z = blockIdx.z;           // r*3+e
  int r = z / 3;
  int count = counts[z];
  int m0 = blockIdx.y * 128;
  if (m0 >= count) return;
  int n0 = blockIdx.x * 128;

  __shared__ alignas(16) unsigned short As[128 * 32];
  __shared__ alignas(16) unsigned short Bs[128 * 32];
  __shared__ int toks[128];
  __shared__ float scl[128];
  __shared__ float bias_s[128];

  int tid = threadIdx.x;
  int lane = tid & 63;
  int w = tid >> 6;

  if (tid < 128) {
    int row = m0 + tid;
    int grow = row < count ? row : count - 1;  // clamp (valid addr, store-guarded)
    int tok = perm[(size_t)z * T + grow];
    toks[tid] = tok;
    scl[tid] = (row < count) ? scale[(size_t)r * T + tok] : 0.0f;
    bias_s[tid] = be[(size_t)z * HH + n0 + tid];
  }
  __syncthreads();

  // staging geometry: 512 x 8-element segments per tile; thread handles tid, tid+256
  int ldsoff[2];
  size_t abase[2], bbase[2];
#pragma unroll
  for (int i = 0; i < 2; ++i) {
    int linear = tid + i * 256;         // [0,512)
    int rowi = linear >> 2;             // 128 rows
    int segi = linear & 3;              // 4 x 8-element segments per row
    int tok = toks[rowi];
    abase[i] = (size_t)(((tok >> 10) * 3 + r) * SS + (tok & 1023)) * HH +
               segi * 8;
    bbase[i] = ((size_t)z * HH + n0 + rowi) * HH + segi * 8;  // W[n][h]
    ldsoff[i] = rowi * 32 + segi * 8;
  }

  int wm = (w >> 1) * 64;
  int wn = (w & 1) * 64;
  floatx4 acc[4][4] = {};

  for (int kk = 0; kk < HH; kk += 32) {
    // issue fp32 global loads early (overlap previous iteration's MFMAs)
    uint4 av[2], bv[2];
#pragma unroll
    for (int i = 0; i < 2; ++i) {
      const float4* ap = reinterpret_cast<const float4*>(x + abase[i] + kk);
      float4 a0 = ap[0], a1 = ap[1];
      const float4* bp = reinterpret_cast<const float4*>(We + bbase[i] + kk);
      float4 b0 = bp[0], b1 = bp[1];
      av[i].x = pack2(a0.x, a0.y); av[i].y = pack2(a0.z, a0.w);
      av[i].z = pack2(a1.x, a1.y); av[i].w = pack2(a1.z, a1.w);
      bv[i].x = pack2(b0.x, b0.y); bv[i].y = pack2(b0.z, b0.w);
      bv[i].z = pack2(b1.x, b1.y); bv[i].w = pack2(b1.z, b1.w);
    }
    __syncthreads();  // previous tile fully consumed
#pragma unroll
    for (int i = 0; i < 2; ++i) {
      *reinterpret_cast<uint4*>(&As[ldsoff[i]]) = av[i];
      *reinterpret_cast<uint4*>(&Bs[ldsoff[i]]) = bv[i];
    }
    __syncthreads();  // tile visible to all waves

    bf16x8 af[4], bq[4];
#pragma unroll
    for (int mt = 0; mt < 4; ++mt)
      af[mt] = *reinterpret_cast<const bf16x8*>(
          &As[(wm + mt * 16 + (lane & 15)) * 32 + (lane >> 4) * 8]);
#pragma unroll
    for (int nt = 0; nt < 4; ++nt)
      bq[nt] = *reinterpret_cast<const bf16x8*>(
          &Bs[(wn + nt * 16 + (lane & 15)) * 32 + (lane >> 4) * 8]);
#pragma unroll
    for (int mt = 0; mt < 4; ++mt)
#pragma unroll
      for (int nt = 0; nt < 4; ++nt)
        acc[mt][nt] = __builtin_amdgcn_mfma_f32_16x16x32_bf16(
            af[mt], bq[nt], acc[mt][nt], 0, 0, 0);
  }

  // epilogue: D row = (lane>>4)*4+reg, col = lane&15 (verified layout)
#pragma unroll
  for (int mt = 0; mt < 4; ++mt) {
#pragma unroll
    for (int rr = 0; rr < 4; ++rr) {
      int ml = wm + mt * 16 + (lane >> 4) * 4 + rr;
      if (m0 + ml < count) {
        float sc = scl[ml];
        int tok = toks[ml];
        size_t ob =
            (size_t)(((tok >> 10) * 3 + r) * SS + (tok & 1023)) * HH + n0;
#pragma unroll
        for (int nt = 0; nt < 4; ++nt) {
          int nl = wn + nt * 16 + (lane & 15);
          out[ob + nl] = sc * (acc[mt][nt][rr] + bias_s[nl]);
        }
      }
    }
  }
}

extern "C" void kernel_launch(void* const* d_in, const int* in_sizes, int n_in,
                              void* d_out, int out_size, void* d_ws,
                              size_t ws_size, hipStream_t stream) {
  const float* feat = (const float*)d_in[0];  // features fp32
  const float* gw   = (const float*)d_in[1];  // gate_w fp32
  const float* ew   = (const float*)d_in[2];  // expert_w fp32
  const float* eb   = (const float*)d_in[3];  // expert_b fp32
  float* out = (float*)d_out;

  int B = in_sizes[0] / (3 * SS * HH);
  int T = B * SS;                  // tokens per branch (8192)
  int C = (T + EE - 1) / EE;       // capacity = ceil(T/E) = 2731

  // workspace layout (ints/floats, 4B): ~576 KB total
  int* perm   = (int*)d_ws;                    // 9*T
  int* counts = perm + (size_t)9 * T;          // 16 (padded)
  int* idxb   = counts + 16;                   // 3*T
  float* gv   = (float*)(idxb + (size_t)3 * T);// 3*T
  float* scl  = gv + (size_t)3 * T;            // 3*T

  int waves = 3 * T;
  k_route<<<dim3((waves + 3) / 4), dim3(256), 0, stream>>>(feat, gw, idxb, gv, T);
  k_scan<<<dim3(3), dim3(1024), 0, stream>>>(idxb, gv, perm, scl, counts, T, C);
  k_gemm<<<dim3(HH / 128, (T + 127) / 128, 9), dim3(256), 0, stream>>>(
      feat, ew, eb, perm, scl, counts, out, T);
}